// Round 1
// baseline (1603.476 us; speedup 1.0000x reference)
//
#include <hip/hip_runtime.h>
#include <hip/hip_bf16.h>
#include <math.h>

#define H 64
#define DM 128
#define GDIM 192      // 3*H
#define BSZ 32
#define SEQ 500
#define NROW (BSZ*SEQ)  // 16000
#define LIBN 2145
#define FFD 128

__device__ __forceinline__ float sigf(float x) {
    return 1.0f / (1.0f + __expf(-x));
}
__device__ __forceinline__ float tanhfast(float x) {
    x = fminf(fmaxf(x, -15.0f), 15.0f);
    float t = __expf(-2.0f * x);
    return (1.0f - t) / (1.0f + t);
}

// ---------------- pack Wih0 (192,128) -> WTp[k4][g][e] for coalesced float4 loads ----
__global__ void pack_wih0(const float* __restrict__ w, float* __restrict__ wt) {
    int idx = blockIdx.x * 256 + threadIdx.x;
    if (idx >= GDIM * DM) return;
    int e  = idx & 3;
    int g  = (idx >> 2) % GDIM;
    int k4 = idx / (GDIM * 4);
    wt[idx] = w[g * DM + k4 * 4 + e];
}

// ---------------- xp0 = x @ Wih0^T + bih0 : (16000,128)@(128,192) ------------------
__global__ __launch_bounds__(192) void xp0_gemm(const float* __restrict__ x,
                                                const float* __restrict__ wtp,
                                                const float* __restrict__ bih0,
                                                float* __restrict__ xp0) {
    __shared__ float xs[64][DM];
    int rb = blockIdx.x * 64;
    for (int idx = threadIdx.x; idx < 64 * 32; idx += 192) {
        int r = idx >> 5, k4 = idx & 31;
        ((float4*)xs[r])[k4] = ((const float4*)(x + (size_t)(rb + r) * DM))[k4];
    }
    __syncthreads();
    int g = threadIdx.x;
    float bias = bih0[g];
    float acc[64];
#pragma unroll
    for (int r = 0; r < 64; r++) acc[r] = bias;
    for (int k4 = 0; k4 < 32; k4++) {
        float4 w4 = ((const float4*)wtp)[k4 * GDIM + g];
#pragma unroll
        for (int r = 0; r < 64; r++) {
            float4 xv = ((float4*)xs[r])[k4];
            acc[r] += w4.x * xv.x + w4.y * xv.y + w4.z * xv.z + w4.w * xv.w;
        }
    }
    for (int r = 0; r < 64; r++) xp0[(size_t)(rb + r) * GDIM + g] = acc[r];
}

// ---------------- fused 2-layer GRU scan; one block per batch element ---------------
// threads: m = tid/192 in {0:gh0, 1:xp1, 2:gh1}, r = tid%192 (weight row in VGPRs).
// Layer-1 skewed one step so all three matvecs run concurrently each step.
__global__ __launch_bounds__(576) void gru_fused(const float* __restrict__ xp0,
                                                 const float* __restrict__ whh0,
                                                 const float* __restrict__ bhh0,
                                                 const float* __restrict__ wih1,
                                                 const float* __restrict__ bih1,
                                                 const float* __restrict__ whh1,
                                                 const float* __restrict__ bhh1,
                                                 float* __restrict__ hbuf) {
    int b = blockIdx.x;
    int tid = threadIdx.x;
    int m = tid / GDIM, r = tid % GDIM;
    __shared__ float h0s[H], h1s[H];
    __shared__ float gh[3][GDIM];
    if (tid < H) { h0s[tid] = 0.0f; h1s[tid] = 0.0f; }

    const float* wsrc = (m == 0 ? whh0 : (m == 1 ? wih1 : whh1)) + (size_t)r * H;
    float w[H];
#pragma unroll
    for (int k = 0; k < 16; k++) {
        float4 t = ((const float4*)wsrc)[k];
        w[4 * k] = t.x; w[4 * k + 1] = t.y; w[4 * k + 2] = t.z; w[4 * k + 3] = t.w;
    }
    float bias = (m == 0 ? bhh0 : (m == 1 ? bih1 : bhh1))[r];

    const float* xpb = xp0 + (size_t)b * SEQ * GDIM;
    float xr_c = 0, xz_c = 0, xn_c = 0, xr_n = 0, xz_n = 0, xn_n = 0;
    if (tid < H) { xr_c = xpb[tid]; xz_c = xpb[H + tid]; xn_c = xpb[2 * H + tid]; }
    __syncthreads();

    for (int s = 0; s <= SEQ; s++) {
        // prefetch xp0 for step s+1 (one full step of latency hiding)
        if (tid < H && s + 1 < SEQ) {
            const float* p = xpb + (size_t)(s + 1) * GDIM;
            xr_n = p[tid]; xz_n = p[H + tid]; xn_n = p[2 * H + tid];
        }
        // matvec: m0: Whh0@h0[s-1]; m1: Wih1@h0[s-1] (=xp1(s-1)); m2: Whh1@h1[s-2]
        const float* hv = (m == 2) ? h1s : h0s;
        float acc = bias;
#pragma unroll
        for (int k4 = 0; k4 < 16; k4++) {
            float4 h4 = ((const float4*)hv)[k4];
            acc += w[4 * k4] * h4.x + w[4 * k4 + 1] * h4.y +
                   w[4 * k4 + 2] * h4.z + w[4 * k4 + 3] * h4.w;
        }
        gh[m][r] = acc;
        __syncthreads();
        if (tid < H) {
            if (s < SEQ) {
                int i = tid;
                float rg = sigf(xr_c + gh[0][i]);
                float zg = sigf(xz_c + gh[0][H + i]);
                float ng = tanhfast(xn_c + rg * gh[0][2 * H + i]);
                h0s[i] = (1.0f - zg) * ng + zg * h0s[i];
                xr_c = xr_n; xz_c = xz_n; xn_c = xn_n;
            }
        } else if (tid < 2 * H) {
            if (s >= 1) {
                int i = tid - H;
                float rg = sigf(gh[1][i] + gh[2][i]);
                float zg = sigf(gh[1][H + i] + gh[2][H + i]);
                float ng = tanhfast(gh[1][2 * H + i] + rg * gh[2][2 * H + i]);
                float h1n = (1.0f - zg) * ng + zg * h1s[i];
                h1s[i] = h1n;
                hbuf[((size_t)b * SEQ + (s - 1)) * H + i] = h1n;
            }
        }
        __syncthreads();
    }
}

// ---------------- fused SINDy layer: theta@coef + LN1 + FFN(gelu) + LN2 ------------
// block = 512 threads (8 waves), 64 rows; lane = row; quad terms k-split across waves.
__global__ __launch_bounds__(512) void sindy_layer_k(float* __restrict__ hbuf,
                                                     const float* __restrict__ coef,
                                                     const float* __restrict__ g1,
                                                     const float* __restrict__ b1n,
                                                     const float* __restrict__ w1,
                                                     const float* __restrict__ bf1,
                                                     const float* __restrict__ w2,
                                                     const float* __restrict__ bf2,
                                                     const float* __restrict__ g2,
                                                     const float* __restrict__ b2n,
                                                     float* __restrict__ out,
                                                     int final_layer) {
    __shared__ float z[64][H + 1];    // input rows, later holds LN1(src+upd)
    __shared__ float upd[64][H + 1];  // theta@coef accumulator, later ff2 accumulator
    __shared__ float ff[64][FFD + 1];

    int row0 = blockIdx.x * 64;
    int tid = threadIdx.x;
    int wv = tid >> 6, lane = tid & 63;

    for (int idx = tid; idx < 64 * H; idx += 512) {
        int r = idx >> 6, c = idx & 63;
        z[r][c] = hbuf[(size_t)(row0 + r) * H + c];
        upd[r][c] = coef[c];  // constant term (l = 0)
    }
    for (int idx = tid; idx < 64 * FFD; idx += 512) {
        int r = idx >> 7, f = idx & 127;
        ff[r][f] = bf1[f];
    }
    __syncthreads();

    // ---- phase 1: theta @ coef (linear terms on wave 0, quad terms 8-way split) ----
    {
        const int ilo_tab[9] = {0, 4, 9, 14, 19, 25, 32, 42, 64};
        int ilo = ilo_tab[wv], ihi = ilo_tab[wv + 1];
        float acc[64];
#pragma unroll
        for (int c = 0; c < 64; c++) acc[c] = 0.0f;
        if (wv == 0) {
            for (int i = 0; i < H; i++) {
                float zi = z[lane][i];
                const float* cp = coef + (size_t)(1 + i) * H;
#pragma unroll
                for (int c = 0; c < 64; c++) acc[c] += zi * cp[c];
            }
        }
        int pb = 64 * ilo - (ilo * (ilo - 1)) / 2;  // quad pairs before row ilo
        const float* cp = coef + (size_t)(1 + H + pb) * H;
        for (int i = ilo; i < ihi; i++) {
            float zi = z[lane][i];
            for (int j = i; j < H; j++) {
                float t = zi * z[lane][j];
#pragma unroll
                for (int c = 0; c < 64; c++) acc[c] += t * cp[c];
                cp += H;
            }
        }
#pragma unroll
        for (int c = 0; c < 64; c++) atomicAdd(&upd[lane][c], acc[c]);
    }
    __syncthreads();

    // ---- phase 2: LN1 (wave 0; lane = row, all in registers) -> z ----
    if (wv == 0) {
        float v[64];
        float s1 = 0.0f;
#pragma unroll
        for (int c = 0; c < 64; c++) { v[c] = z[lane][c] + upd[lane][c]; s1 += v[c]; }
        float mn = s1 * (1.0f / 64.0f);
        float s2 = 0.0f;
#pragma unroll
        for (int c = 0; c < 64; c++) { float d = v[c] - mn; s2 += d * d; }
        float rstd = 1.0f / sqrtf(s2 * (1.0f / 64.0f) + 1e-5f);
#pragma unroll
        for (int c = 0; c < 64; c++) z[lane][c] = (v[c] - mn) * rstd * g1[c] + b1n[c];
    }
    __syncthreads();
    // re-init upd as the ff2 accumulator (bias b2 of second linear)
    for (int idx = tid; idx < 64 * H; idx += 512) {
        int r = idx >> 6, c = idx & 63;
        upd[r][c] = bf2[c];
    }

    // ---- phase 3: ff1 = srcln @ W1^T + b1 (k-split 8x8 across waves) ----
    {
        int k0 = wv * 8;
        float sv[8];
#pragma unroll
        for (int kk = 0; kk < 8; kk++) sv[kk] = z[lane][k0 + kk];
        for (int f = 0; f < FFD; f++) {
            const float* wr = w1 + (size_t)f * H + k0;
            float p = 0.0f;
#pragma unroll
            for (int kk = 0; kk < 8; kk++) p += sv[kk] * wr[kk];
            atomicAdd(&ff[lane][f], p);
        }
    }
    __syncthreads();

    // ---- phase 4: exact GELU ----
    for (int idx = tid; idx < 64 * FFD; idx += 512) {
        int r = idx >> 7, f = idx & 127;
        float v = ff[r][f];
        ff[r][f] = 0.5f * v * (1.0f + erff(v * 0.70710678118654752f));
    }
    __syncthreads();

    // ---- phase 5: ff2 = gelu @ W2^T (k-split 8x16 across waves) ----
    {
        int k0 = wv * 16;
        float gv[16];
#pragma unroll
        for (int kk = 0; kk < 16; kk++) gv[kk] = ff[lane][k0 + kk];
        for (int c = 0; c < H; c++) {
            const float* wr = w2 + (size_t)c * FFD + k0;
            float p = 0.0f;
#pragma unroll
            for (int kk = 0; kk < 16; kk++) p += gv[kk] * wr[kk];
            atomicAdd(&upd[lane][c], p);
        }
    }
    __syncthreads();

    // ---- phase 6: LN2 + write (wave 0) ----
    if (wv == 0) {
        float v[64];
        float s1 = 0.0f;
#pragma unroll
        for (int c = 0; c < 64; c++) { v[c] = z[lane][c] + upd[lane][c]; s1 += v[c]; }
        float mn = s1 * (1.0f / 64.0f);
        float s2 = 0.0f;
#pragma unroll
        for (int c = 0; c < 64; c++) { float d = v[c] - mn; s2 += d * d; }
        float rstd = 1.0f / sqrtf(s2 * (1.0f / 64.0f) + 1e-5f);
        int row = row0 + lane;
#pragma unroll
        for (int c = 0; c < 64; c++) {
            float res = (v[c] - mn) * rstd * g2[c] + b2n[c];
            if (!final_layer) {
                hbuf[(size_t)row * H + c] = res;
            } else {
                out[(size_t)row * H + c] = res;
                if (row % SEQ == SEQ - 1)
                    out[(size_t)NROW * H + (row / SEQ) * H + c] = res;
            }
        }
    }
}

extern "C" void kernel_launch(void* const* d_in, const int* in_sizes, int n_in,
                              void* d_out, int out_size, void* d_ws, size_t ws_size,
                              hipStream_t stream) {
    const float* x    = (const float*)d_in[0];
    const float* wih0 = (const float*)d_in[1];
    const float* whh0 = (const float*)d_in[2];
    const float* bih0 = (const float*)d_in[3];
    const float* bhh0 = (const float*)d_in[4];
    const float* wih1 = (const float*)d_in[5];
    const float* whh1 = (const float*)d_in[6];
    const float* bih1 = (const float*)d_in[7];
    const float* bhh1 = (const float*)d_in[8];
    const float* coeffs = (const float*)d_in[9];
    const float* ln1g = (const float*)d_in[10];
    const float* ln1b = (const float*)d_in[11];
    const float* w1   = (const float*)d_in[12];
    const float* b1   = (const float*)d_in[13];
    const float* w2   = (const float*)d_in[14];
    const float* b2   = (const float*)d_in[15];
    const float* ln2g = (const float*)d_in[16];
    const float* ln2b = (const float*)d_in[17];

    float* out = (float*)d_out;
    float* ws  = (float*)d_ws;
    float* xp0 = ws;                          // 16000*192 floats = 12.29 MB
    float* wtp = ws + (size_t)NROW * GDIM;    // 24576 floats
    float* hbuf = out;                        // reuse first 1,024,000 floats of d_out

    pack_wih0<<<(GDIM * DM + 255) / 256, 256, 0, stream>>>(wih0, wtp);
    xp0_gemm<<<NROW / 64, 192, 0, stream>>>(x, wtp, bih0, xp0);
    gru_fused<<<BSZ, 576, 0, stream>>>(xp0, whh0, bhh0, wih1, bih1, whh1, bhh1, hbuf);
    for (int l = 0; l < 2; l++) {
        sindy_layer_k<<<NROW / 64, 512, 0, stream>>>(
            hbuf, coeffs + (size_t)l * LIBN * H,
            ln1g + l * H, ln1b + l * H,
            w1 + (size_t)l * FFD * H, b1 + l * FFD,
            w2 + (size_t)l * H * FFD, b2 + l * H,
            ln2g + l * H, ln2b + l * H,
            out, l == 1);
    }
}

// Round 2
// 1164.416 us; speedup vs baseline: 1.3771x; 1.3771x over previous
//
#include <hip/hip_runtime.h>
#include <hip/hip_bf16.h>
#include <math.h>

#define H 64
#define DM 128
#define GDIM 192      // 3*H
#define BSZ 32
#define SEQ 500
#define NROW (BSZ*SEQ)  // 16000
#define LIBN 2145
#define FFD 128

__device__ __forceinline__ float sigf(float x) {
    return 1.0f / (1.0f + __expf(-x));
}
__device__ __forceinline__ float tanhfast(float x) {
    x = fminf(fmaxf(x, -15.0f), 15.0f);
    float t = __expf(-2.0f * x);
    return (1.0f - t) / (1.0f + t);
}

// ---------------- pack Wih0 (192,128) -> WTp[k4][g][e] for coalesced float4 loads ----
__global__ void pack_wih0(const float* __restrict__ w, float* __restrict__ wt) {
    int idx = blockIdx.x * 256 + threadIdx.x;
    if (idx >= GDIM * DM) return;
    int e  = idx & 3;
    int g  = (idx >> 2) % GDIM;
    int k4 = idx / (GDIM * 4);
    wt[idx] = w[g * DM + k4 * 4 + e];
}

// ---------------- xp0 = x @ Wih0^T + bih0 : (16000,128)@(128,192) ------------------
__global__ __launch_bounds__(192) void xp0_gemm(const float* __restrict__ x,
                                                const float* __restrict__ wtp,
                                                const float* __restrict__ bih0,
                                                float* __restrict__ xp0) {
    __shared__ float xs[64][DM];
    int rb = blockIdx.x * 64;
    for (int idx = threadIdx.x; idx < 64 * 32; idx += 192) {
        int r = idx >> 5, k4 = idx & 31;
        ((float4*)xs[r])[k4] = ((const float4*)(x + (size_t)(rb + r) * DM))[k4];
    }
    __syncthreads();
    int g = threadIdx.x;
    float bias = bih0[g];
    float acc[64];
#pragma unroll
    for (int r = 0; r < 64; r++) acc[r] = bias;
    for (int k4 = 0; k4 < 32; k4++) {
        float4 w4 = ((const float4*)wtp)[k4 * GDIM + g];
#pragma unroll
        for (int r = 0; r < 64; r++) {
            float4 xv = ((float4*)xs[r])[k4];
            acc[r] += w4.x * xv.x + w4.y * xv.y + w4.z * xv.z + w4.w * xv.w;
        }
    }
    for (int r = 0; r < 64; r++) xp0[(size_t)(rb + r) * GDIM + g] = acc[r];
}

// ---------------- fused 2-layer GRU scan; one block per batch element ---------------
// 3 waves/block. Wave w owns one matvec (w0: Whh0@h0, w1: Wih1@h0, w2: Whh1@h1);
// lane i owns output rows {i, 64+i, 128+i} so the r,z,n gate inputs for h[i] land in
// the SAME lane -> gate update is local, no LDS broadcast. h[k] broadcast for the dot
// product comes from v_readlane (VALU), eliminating the 147 KB/step LDS traffic.
__global__ __launch_bounds__(192, 1) void gru_fused(const float* __restrict__ xp0,
                                                    const float* __restrict__ whh0,
                                                    const float* __restrict__ bhh0,
                                                    const float* __restrict__ wih1,
                                                    const float* __restrict__ bih1,
                                                    const float* __restrict__ whh1,
                                                    const float* __restrict__ bhh1,
                                                    float* __restrict__ hbuf) {
    int b = blockIdx.x;
    int tid = threadIdx.x;
    int wv = __builtin_amdgcn_readfirstlane(tid >> 6);
    int i = tid & 63;

    __shared__ float xp1s[GDIM];
    __shared__ float h0s[H];

    const float* W  = (wv == 0) ? whh0 : (wv == 1) ? wih1 : whh1;
    const float* bs = (wv == 0) ? bhh0 : (wv == 1) ? bih1 : bhh1;

    float wr[H], wz[H], wn[H];
#pragma unroll
    for (int k4 = 0; k4 < 16; k4++) {
        float4 a = ((const float4*)(W + (size_t)i * H))[k4];
        float4 c = ((const float4*)(W + (size_t)(H + i) * H))[k4];
        float4 d = ((const float4*)(W + (size_t)(2 * H + i) * H))[k4];
        wr[4 * k4] = a.x; wr[4 * k4 + 1] = a.y; wr[4 * k4 + 2] = a.z; wr[4 * k4 + 3] = a.w;
        wz[4 * k4] = c.x; wz[4 * k4 + 1] = c.y; wz[4 * k4 + 2] = c.z; wz[4 * k4 + 3] = c.w;
        wn[4 * k4] = d.x; wn[4 * k4 + 1] = d.y; wn[4 * k4 + 2] = d.z; wn[4 * k4 + 3] = d.w;
    }
    float br_ = bs[i], bz_ = bs[H + i], bn_ = bs[2 * H + i];

    float hreg = 0.0f;  // w0: h0[i]; w1: lagged copy of h0[i]; w2: h1[i]
    const float* xpb = xp0 + (size_t)b * SEQ * GDIM;
    float xr_c = 0, xz_c = 0, xn_c = 0, xr_n = 0, xz_n = 0, xn_n = 0;
    if (wv == 0) { xr_c = xpb[i]; xz_c = xpb[H + i]; xn_c = xpb[2 * H + i]; }

    for (int s = 0; s <= SEQ; s++) {
        // prefetch xp0 for step s+1 (wave 0 only), issued before the matvec
        if (wv == 0 && s + 1 < SEQ) {
            const float* p = xpb + (size_t)(s + 1) * GDIM;
            xr_n = p[i]; xz_n = p[H + i]; xn_n = p[2 * H + i];
        }
        // matvec: acc_{r,z,n} = W_{row}{i,64+i,128+i} . h + bias, h broadcast by readlane
        float ar = br_, az = bz_, an = bn_;
#pragma unroll
        for (int k = 0; k < H; k++) {
            float hk = __uint_as_float(
                __builtin_amdgcn_readlane(__float_as_uint(hreg), k));
            ar += hk * wr[k];
            az += hk * wz[k];
            an += hk * wn[k];
        }
        if (wv == 1) { xp1s[i] = ar; xp1s[H + i] = az; xp1s[2 * H + i] = an; }
        __syncthreads();
        if (wv == 0) {
            if (s < SEQ) {
                float rg = sigf(xr_c + ar);
                float zg = sigf(xz_c + az);
                float ng = tanhfast(xn_c + rg * an);
                hreg = (1.0f - zg) * ng + zg * hreg;
                h0s[i] = hreg;
                xr_c = xr_n; xz_c = xz_n; xn_c = xn_n;
            }
        } else if (wv == 2) {
            if (s >= 1) {
                float xr1 = xp1s[i], xz1 = xp1s[H + i], xn1 = xp1s[2 * H + i];
                float rg = sigf(xr1 + ar);
                float zg = sigf(xz1 + az);
                float ng = tanhfast(xn1 + rg * an);
                hreg = (1.0f - zg) * ng + zg * hreg;
                hbuf[((size_t)b * SEQ + (s - 1)) * H + i] = hreg;
            }
        }
        __syncthreads();
        if (wv == 1) hreg = h0s[i];  // wave1's next xp1 uses h0[s]
    }
}

// ---------------- fused SINDy layer: theta@coef + LN1 + FFN(gelu) + LN2 ------------
// block = 512 threads (8 waves), 64 rows; lane = row; quad terms k-split across waves.
// wv forced wave-uniform (readfirstlane) so all weight-row pointers are SGPR-uniform
// -> coef/w1/w2 accesses compile to scalar (s_load) instead of 64 divergent loads.
__global__ __launch_bounds__(512) void sindy_layer_k(float* __restrict__ hbuf,
                                                     const float* __restrict__ coef,
                                                     const float* __restrict__ g1,
                                                     const float* __restrict__ b1n,
                                                     const float* __restrict__ w1,
                                                     const float* __restrict__ bf1,
                                                     const float* __restrict__ w2,
                                                     const float* __restrict__ bf2,
                                                     const float* __restrict__ g2,
                                                     const float* __restrict__ b2n,
                                                     float* __restrict__ out,
                                                     int final_layer) {
    __shared__ float z[64][H + 1];    // input rows, later holds LN1(src+upd)
    __shared__ float upd[64][H + 1];  // theta@coef accumulator, later ff2 accumulator
    __shared__ float ff[64][FFD + 1];

    int row0 = blockIdx.x * 64;
    int tid = threadIdx.x;
    int wv = __builtin_amdgcn_readfirstlane(tid >> 6);
    int lane = tid & 63;

    for (int idx = tid; idx < 64 * H; idx += 512) {
        int r = idx >> 6, c = idx & 63;
        z[r][c] = hbuf[(size_t)(row0 + r) * H + c];
        upd[r][c] = coef[c];  // constant term (l = 0)
    }
    for (int idx = tid; idx < 64 * FFD; idx += 512) {
        int r = idx >> 7, f = idx & 127;
        ff[r][f] = bf1[f];
    }
    __syncthreads();

    // ---- phase 1: theta @ coef (linear terms on wave 0, quad terms 8-way split) ----
    {
        const int ilo_tab[9] = {0, 4, 9, 14, 19, 25, 32, 42, 64};
        int ilo = ilo_tab[wv], ihi = ilo_tab[wv + 1];
        float acc[64];
#pragma unroll
        for (int c = 0; c < 64; c++) acc[c] = 0.0f;
        if (wv == 0) {
            for (int i = 0; i < H; i++) {
                float zi = z[lane][i];
                const float* cp = coef + (size_t)(1 + i) * H;
#pragma unroll
                for (int c = 0; c < 64; c++) acc[c] += zi * cp[c];
            }
        }
        int pb = 64 * ilo - (ilo * (ilo - 1)) / 2;  // quad pairs before row ilo
        const float* cp = coef + (size_t)(1 + H + pb) * H;
        for (int i = ilo; i < ihi; i++) {
            float zi = z[lane][i];
            for (int j = i; j < H; j++) {
                float t = zi * z[lane][j];
#pragma unroll
                for (int c = 0; c < 64; c++) acc[c] += t * cp[c];
                cp += H;
            }
        }
#pragma unroll
        for (int c = 0; c < 64; c++) atomicAdd(&upd[lane][c], acc[c]);
    }
    __syncthreads();

    // ---- phase 2: LN1 (wave 0; lane = row, all in registers) -> z ----
    if (wv == 0) {
        float v[64];
        float s1 = 0.0f;
#pragma unroll
        for (int c = 0; c < 64; c++) { v[c] = z[lane][c] + upd[lane][c]; s1 += v[c]; }
        float mn = s1 * (1.0f / 64.0f);
        float s2 = 0.0f;
#pragma unroll
        for (int c = 0; c < 64; c++) { float d = v[c] - mn; s2 += d * d; }
        float rstd = 1.0f / sqrtf(s2 * (1.0f / 64.0f) + 1e-5f);
#pragma unroll
        for (int c = 0; c < 64; c++) z[lane][c] = (v[c] - mn) * rstd * g1[c] + b1n[c];
    }
    __syncthreads();
    // re-init upd as the ff2 accumulator (bias b2 of second linear)
    for (int idx = tid; idx < 64 * H; idx += 512) {
        int r = idx >> 6, c = idx & 63;
        upd[r][c] = bf2[c];
    }

    // ---- phase 3: ff1 = srcln @ W1^T + b1 (k-split 8x8 across waves) ----
    {
        int k0 = wv * 8;
        float sv[8];
#pragma unroll
        for (int kk = 0; kk < 8; kk++) sv[kk] = z[lane][k0 + kk];
        for (int f = 0; f < FFD; f++) {
            const float* wr = w1 + (size_t)f * H + k0;
            float p = 0.0f;
#pragma unroll
            for (int kk = 0; kk < 8; kk++) p += sv[kk] * wr[kk];
            atomicAdd(&ff[lane][f], p);
        }
    }
    __syncthreads();

    // ---- phase 4: exact GELU ----
    for (int idx = tid; idx < 64 * FFD; idx += 512) {
        int r = idx >> 7, f = idx & 127;
        float v = ff[r][f];
        ff[r][f] = 0.5f * v * (1.0f + erff(v * 0.70710678118654752f));
    }
    __syncthreads();

    // ---- phase 5: ff2 = gelu @ W2^T (k-split 8x16 across waves) ----
    {
        int k0 = wv * 16;
        float gv[16];
#pragma unroll
        for (int kk = 0; kk < 16; kk++) gv[kk] = ff[lane][k0 + kk];
        for (int c = 0; c < H; c++) {
            const float* wr = w2 + (size_t)c * FFD + k0;
            float p = 0.0f;
#pragma unroll
            for (int kk = 0; kk < 16; kk++) p += gv[kk] * wr[kk];
            atomicAdd(&upd[lane][c], p);
        }
    }
    __syncthreads();

    // ---- phase 6: LN2 + write (wave 0) ----
    if (wv == 0) {
        float v[64];
        float s1 = 0.0f;
#pragma unroll
        for (int c = 0; c < 64; c++) { v[c] = z[lane][c] + upd[lane][c]; s1 += v[c]; }
        float mn = s1 * (1.0f / 64.0f);
        float s2 = 0.0f;
#pragma unroll
        for (int c = 0; c < 64; c++) { float d = v[c] - mn; s2 += d * d; }
        float rstd = 1.0f / sqrtf(s2 * (1.0f / 64.0f) + 1e-5f);
        int row = row0 + lane;
#pragma unroll
        for (int c = 0; c < 64; c++) {
            float res = (v[c] - mn) * rstd * g2[c] + b2n[c];
            if (!final_layer) {
                hbuf[(size_t)row * H + c] = res;
            } else {
                out[(size_t)row * H + c] = res;
                if (row % SEQ == SEQ - 1)
                    out[(size_t)NROW * H + (row / SEQ) * H + c] = res;
            }
        }
    }
}

extern "C" void kernel_launch(void* const* d_in, const int* in_sizes, int n_in,
                              void* d_out, int out_size, void* d_ws, size_t ws_size,
                              hipStream_t stream) {
    const float* x    = (const float*)d_in[0];
    const float* wih0 = (const float*)d_in[1];
    const float* whh0 = (const float*)d_in[2];
    const float* bih0 = (const float*)d_in[3];
    const float* bhh0 = (const float*)d_in[4];
    const float* wih1 = (const float*)d_in[5];
    const float* whh1 = (const float*)d_in[6];
    const float* bih1 = (const float*)d_in[7];
    const float* bhh1 = (const float*)d_in[8];
    const float* coeffs = (const float*)d_in[9];
    const float* ln1g = (const float*)d_in[10];
    const float* ln1b = (const float*)d_in[11];
    const float* w1   = (const float*)d_in[12];
    const float* b1   = (const float*)d_in[13];
    const float* w2   = (const float*)d_in[14];
    const float* b2   = (const float*)d_in[15];
    const float* ln2g = (const float*)d_in[16];
    const float* ln2b = (const float*)d_in[17];

    float* out = (float*)d_out;
    float* ws  = (float*)d_ws;
    float* xp0 = ws;                          // 16000*192 floats = 12.29 MB
    float* wtp = ws + (size_t)NROW * GDIM;    // 24576 floats
    float* hbuf = out;                        // reuse first 1,024,000 floats of d_out

    pack_wih0<<<(GDIM * DM + 255) / 256, 256, 0, stream>>>(wih0, wtp);
    xp0_gemm<<<NROW / 64, 192, 0, stream>>>(x, wtp, bih0, xp0);
    gru_fused<<<BSZ, 192, 0, stream>>>(xp0, whh0, bhh0, wih1, bih1, whh1, bhh1, hbuf);
    for (int l = 0; l < 2; l++) {
        sindy_layer_k<<<NROW / 64, 512, 0, stream>>>(
            hbuf, coeffs + (size_t)l * LIBN * H,
            ln1g + l * H, ln1b + l * H,
            w1 + (size_t)l * FFD * H, b1 + l * FFD,
            w2 + (size_t)l * H * FFD, b2 + l * H,
            ln2g + l * H, ln2b + l * H,
            out, l == 1);
    }
}

// Round 3
// 1000.998 us; speedup vs baseline: 1.6019x; 1.1633x over previous
//
#include <hip/hip_runtime.h>
#include <hip/hip_bf16.h>
#include <math.h>

#define H 64
#define DM 128
#define GDIM 192      // 3*H
#define BSZ 32
#define SEQ 500
#define NROW (BSZ*SEQ)  // 16000
#define LIBN 2145
#define FFD 128

__device__ __forceinline__ float sigf(float x) {
    return 1.0f / (1.0f + __expf(-x));
}
__device__ __forceinline__ float tanhfast(float x) {
    x = fminf(fmaxf(x, -15.0f), 15.0f);
    float t = __expf(-2.0f * x);
    return (1.0f - t) / (1.0f + t);
}

// ---------------- pack Wih0 (192,128) -> WTp[k4][g][e] for coalesced float4 loads ----
__global__ void pack_wih0(const float* __restrict__ w, float* __restrict__ wt) {
    int idx = blockIdx.x * 256 + threadIdx.x;
    if (idx >= GDIM * DM) return;
    int e  = idx & 3;
    int g  = (idx >> 2) % GDIM;
    int k4 = idx / (GDIM * 4);
    wt[idx] = w[g * DM + k4 * 4 + e];
}

// ---------------- xp0 = x @ Wih0^T + bih0 : (16000,128)@(128,192) ------------------
__global__ __launch_bounds__(192, 2) void xp0_gemm(const float* __restrict__ x,
                                                   const float* __restrict__ wtp,
                                                   const float* __restrict__ bih0,
                                                   float* __restrict__ xp0) {
    __shared__ float xs[64][DM];
    int rb = blockIdx.x * 64;
    for (int idx = threadIdx.x; idx < 64 * 32; idx += 192) {
        int r = idx >> 5, k4 = idx & 31;
        ((float4*)xs[r])[k4] = ((const float4*)(x + (size_t)(rb + r) * DM))[k4];
    }
    __syncthreads();
    int g = threadIdx.x;
    float bias = bih0[g];
    float acc[64];
#pragma unroll
    for (int r = 0; r < 64; r++) acc[r] = bias;
    for (int k4 = 0; k4 < 32; k4++) {
        float4 w4 = ((const float4*)wtp)[k4 * GDIM + g];
#pragma unroll
        for (int r = 0; r < 64; r++) {
            float4 xv = ((float4*)xs[r])[k4];
            acc[r] += w4.x * xv.x + w4.y * xv.y + w4.z * xv.z + w4.w * xv.w;
        }
    }
    for (int r = 0; r < 64; r++) xp0[(size_t)(rb + r) * GDIM + g] = acc[r];
}

// ---------------- fused 2-layer GRU scan; one block per batch element ---------------
// 12 waves. Wave (m = wv%3, q = wv/3) computes K-chunk [16q,16q+16) of matvec m
// (m0: Whh0@h0, m1: Wih1@h0, m2: Whh1@h1). Lane i owns output rows {i,64+i,128+i}
// -> only 48 persistent weight floats per lane (no spill at 3 waves/SIMD).
// Partials reduced via LDS part[m][q][192]; gate waves (wv0: layer0, wv2: layer1)
// sum 4 chunks + biases + xp and update h. Layer 1 runs one step skewed.
__global__ __launch_bounds__(768, 3) void gru_fused(const float* __restrict__ xp0,
                                                    const float* __restrict__ whh0,
                                                    const float* __restrict__ bhh0,
                                                    const float* __restrict__ wih1,
                                                    const float* __restrict__ bih1,
                                                    const float* __restrict__ whh1,
                                                    const float* __restrict__ bhh1,
                                                    float* __restrict__ hbuf) {
    int b = blockIdx.x;
    int tid = threadIdx.x;
    int wv = __builtin_amdgcn_readfirstlane(tid >> 6);
    int lane = tid & 63;
    int m = wv % 3;   // uniform
    int q = wv / 3;   // uniform
    int k0 = q * 16;

    __shared__ __align__(16) float h0s[H];
    __shared__ __align__(16) float h1s[H];
    __shared__ float part[3][4][GDIM];

    if (tid < H) { h0s[tid] = 0.0f; h1s[tid] = 0.0f; }

    const float* W = (m == 0) ? whh0 : (m == 1) ? wih1 : whh1;
    float wr[16], wz[16], wn[16];
#pragma unroll
    for (int k4 = 0; k4 < 4; k4++) {
        float4 a = ((const float4*)(W + (size_t)lane * H + k0))[k4];
        float4 c = ((const float4*)(W + (size_t)(H + lane) * H + k0))[k4];
        float4 d = ((const float4*)(W + (size_t)(2 * H + lane) * H + k0))[k4];
        wr[4 * k4] = a.x; wr[4 * k4 + 1] = a.y; wr[4 * k4 + 2] = a.z; wr[4 * k4 + 3] = a.w;
        wz[4 * k4] = c.x; wz[4 * k4 + 1] = c.y; wz[4 * k4 + 2] = c.z; wz[4 * k4 + 3] = c.w;
        wn[4 * k4] = d.x; wn[4 * k4 + 1] = d.y; wn[4 * k4 + 2] = d.z; wn[4 * k4 + 3] = d.w;
    }

    // gate-wave private state
    float b0r = 0, b0z = 0, b0n = 0;
    float b1ir = 0, b1iz = 0, b1in = 0, b1hr = 0, b1hz = 0, b1hn = 0;
    float hreg0 = 0.0f, hreg1 = 0.0f;
    const float* xpb = xp0 + (size_t)b * SEQ * GDIM;
    float xr_c = 0, xz_c = 0, xn_c = 0, xr_n = 0, xz_n = 0, xn_n = 0;
    if (wv == 0) {
        b0r = bhh0[lane]; b0z = bhh0[H + lane]; b0n = bhh0[2 * H + lane];
        xr_c = xpb[lane]; xz_c = xpb[H + lane]; xn_c = xpb[2 * H + lane];
    } else if (wv == 2) {
        b1ir = bih1[lane]; b1iz = bih1[H + lane]; b1in = bih1[2 * H + lane];
        b1hr = bhh1[lane]; b1hz = bhh1[H + lane]; b1hn = bhh1[2 * H + lane];
    }
    __syncthreads();

    for (int s = 0; s <= SEQ; s++) {
        // prefetch xp0 for step s+1 (wave 0), consumed at gate of iter s+1
        if (wv == 0 && s + 1 < SEQ) {
            const float* p = xpb + (size_t)(s + 1) * GDIM;
            xr_n = p[lane]; xz_n = p[H + lane]; xn_n = p[2 * H + lane];
        }
        // phase 1: partial matvec over K-chunk [k0, k0+16)
        const float* hv = (m == 2) ? h1s : h0s;
        float ar = 0, az = 0, an = 0;
#pragma unroll
        for (int t4 = 0; t4 < 4; t4++) {
            float4 h4 = ((const float4*)(hv + k0))[t4];
            ar += wr[4 * t4] * h4.x + wr[4 * t4 + 1] * h4.y +
                  wr[4 * t4 + 2] * h4.z + wr[4 * t4 + 3] * h4.w;
            az += wz[4 * t4] * h4.x + wz[4 * t4 + 1] * h4.y +
                  wz[4 * t4 + 2] * h4.z + wz[4 * t4 + 3] * h4.w;
            an += wn[4 * t4] * h4.x + wn[4 * t4 + 1] * h4.y +
                  wn[4 * t4 + 2] * h4.z + wn[4 * t4 + 3] * h4.w;
        }
        part[m][q][lane] = ar;
        part[m][q][H + lane] = az;
        part[m][q][2 * H + lane] = an;
        __syncthreads();

        // phase 2: gates
        if (wv == 0) {
            if (s < SEQ) {
                float gr = b0r, gz = b0z, gn = b0n;
#pragma unroll
                for (int qq = 0; qq < 4; qq++) {
                    gr += part[0][qq][lane];
                    gz += part[0][qq][H + lane];
                    gn += part[0][qq][2 * H + lane];
                }
                float rg = sigf(xr_c + gr);
                float zg = sigf(xz_c + gz);
                float ng = tanhfast(xn_c + rg * gn);
                hreg0 = (1.0f - zg) * ng + zg * hreg0;
                h0s[lane] = hreg0;
                xr_c = xr_n; xz_c = xz_n; xn_c = xn_n;
            }
        } else if (wv == 2) {
            if (s >= 1) {
                float xr1 = b1ir, xz1 = b1iz, xn1 = b1in;
                float gr1 = b1hr, gz1 = b1hz, gn1 = b1hn;
#pragma unroll
                for (int qq = 0; qq < 4; qq++) {
                    xr1 += part[1][qq][lane];
                    xz1 += part[1][qq][H + lane];
                    xn1 += part[1][qq][2 * H + lane];
                    gr1 += part[2][qq][lane];
                    gz1 += part[2][qq][H + lane];
                    gn1 += part[2][qq][2 * H + lane];
                }
                float rg = sigf(xr1 + gr1);
                float zg = sigf(xz1 + gz1);
                float ng = tanhfast(xn1 + rg * gn1);
                hreg1 = (1.0f - zg) * ng + zg * hreg1;
                h1s[lane] = hreg1;
                hbuf[((size_t)b * SEQ + (s - 1)) * H + lane] = hreg1;
            }
        }
        __syncthreads();
    }
}

// ---------------- fused SINDy layer: theta@coef + LN1 + FFN(gelu) + LN2 ------------
// block = 512 threads (8 waves), 64 rows; lane = row; quad terms k-split across waves.
// __launch_bounds__(512,2): VGPR cap ~256 so acc[64] stays resident (no scratch).
__global__ __launch_bounds__(512, 2) void sindy_layer_k(float* __restrict__ hbuf,
                                                        const float* __restrict__ coef,
                                                        const float* __restrict__ g1,
                                                        const float* __restrict__ b1n,
                                                        const float* __restrict__ w1,
                                                        const float* __restrict__ bf1,
                                                        const float* __restrict__ w2,
                                                        const float* __restrict__ bf2,
                                                        const float* __restrict__ g2,
                                                        const float* __restrict__ b2n,
                                                        float* __restrict__ out,
                                                        int final_layer) {
    __shared__ float z[64][H + 1];    // input rows, later holds LN1(src+upd)
    __shared__ float upd[64][H + 1];  // theta@coef accumulator, later ff2 accumulator
    __shared__ float ff[64][FFD + 1];

    int row0 = blockIdx.x * 64;
    int tid = threadIdx.x;
    int wv = __builtin_amdgcn_readfirstlane(tid >> 6);
    int lane = tid & 63;

    for (int idx = tid; idx < 64 * H; idx += 512) {
        int r = idx >> 6, c = idx & 63;
        z[r][c] = hbuf[(size_t)(row0 + r) * H + c];
        upd[r][c] = coef[c];  // constant term (l = 0)
    }
    for (int idx = tid; idx < 64 * FFD; idx += 512) {
        int r = idx >> 7, f = idx & 127;
        ff[r][f] = bf1[f];
    }
    __syncthreads();

    // ---- phase 1: theta @ coef (linear terms on wave 0, quad terms 8-way split) ----
    {
        int ilo, ihi;
        switch (wv) {
            case 0:  ilo = 0;  ihi = 4;  break;
            case 1:  ilo = 4;  ihi = 9;  break;
            case 2:  ilo = 9;  ihi = 14; break;
            case 3:  ilo = 14; ihi = 19; break;
            case 4:  ilo = 19; ihi = 25; break;
            case 5:  ilo = 25; ihi = 32; break;
            case 6:  ilo = 32; ihi = 42; break;
            default: ilo = 42; ihi = 64; break;
        }
        float acc[64];
#pragma unroll
        for (int c = 0; c < 64; c++) acc[c] = 0.0f;
        if (wv == 0) {
            const float4* cp4 = (const float4*)(coef + H);  // linear rows 1..64
            for (int i = 0; i < H; i++) {
                float zi = z[lane][i];
#pragma unroll
                for (int c4 = 0; c4 < 16; c4++) {
                    float4 cv = cp4[c4];
                    acc[4 * c4 + 0] += zi * cv.x;
                    acc[4 * c4 + 1] += zi * cv.y;
                    acc[4 * c4 + 2] += zi * cv.z;
                    acc[4 * c4 + 3] += zi * cv.w;
                }
                cp4 += 16;
            }
        }
        int pb = 64 * ilo - (ilo * (ilo - 1)) / 2;  // quad pairs before row ilo
        const float4* cp4 = (const float4*)(coef + (size_t)(1 + H + pb) * H);
        for (int i = ilo; i < ihi; i++) {
            float zi = z[lane][i];
            for (int j = i; j < H; j++) {
                float t = zi * z[lane][j];
#pragma unroll
                for (int c4 = 0; c4 < 16; c4++) {
                    float4 cv = cp4[c4];
                    acc[4 * c4 + 0] += t * cv.x;
                    acc[4 * c4 + 1] += t * cv.y;
                    acc[4 * c4 + 2] += t * cv.z;
                    acc[4 * c4 + 3] += t * cv.w;
                }
                cp4 += 16;
            }
        }
#pragma unroll
        for (int c = 0; c < 64; c++) atomicAdd(&upd[lane][c], acc[c]);
    }
    __syncthreads();

    // ---- phase 2: LN1 (wave 0; lane = row, all in registers) -> z ----
    if (wv == 0) {
        float v[64];
        float s1 = 0.0f;
#pragma unroll
        for (int c = 0; c < 64; c++) { v[c] = z[lane][c] + upd[lane][c]; s1 += v[c]; }
        float mn = s1 * (1.0f / 64.0f);
        float s2 = 0.0f;
#pragma unroll
        for (int c = 0; c < 64; c++) { float d = v[c] - mn; s2 += d * d; }
        float rstd = 1.0f / sqrtf(s2 * (1.0f / 64.0f) + 1e-5f);
#pragma unroll
        for (int c = 0; c < 64; c++) z[lane][c] = (v[c] - mn) * rstd * g1[c] + b1n[c];
    }
    __syncthreads();
    // re-init upd as the ff2 accumulator (bias b2 of second linear)
    for (int idx = tid; idx < 64 * H; idx += 512) {
        int r = idx >> 6, c = idx & 63;
        upd[r][c] = bf2[c];
    }

    // ---- phase 3: ff1 = srcln @ W1^T + b1 (k-split 8x8 across waves) ----
    {
        int k0 = wv * 8;
        float sv[8];
#pragma unroll
        for (int kk = 0; kk < 8; kk++) sv[kk] = z[lane][k0 + kk];
        for (int f = 0; f < FFD; f++) {
            const float4* wr4 = (const float4*)(w1 + (size_t)f * H + k0);
            float4 a = wr4[0], bq = wr4[1];
            float p = sv[0] * a.x + sv[1] * a.y + sv[2] * a.z + sv[3] * a.w +
                      sv[4] * bq.x + sv[5] * bq.y + sv[6] * bq.z + sv[7] * bq.w;
            atomicAdd(&ff[lane][f], p);
        }
    }
    __syncthreads();

    // ---- phase 4: exact GELU ----
    for (int idx = tid; idx < 64 * FFD; idx += 512) {
        int r = idx >> 7, f = idx & 127;
        float v = ff[r][f];
        ff[r][f] = 0.5f * v * (1.0f + erff(v * 0.70710678118654752f));
    }
    __syncthreads();

    // ---- phase 5: ff2 = gelu @ W2^T (k-split 8x16 across waves) ----
    {
        int k0 = wv * 16;
        float gv[16];
#pragma unroll
        for (int kk = 0; kk < 16; kk++) gv[kk] = ff[lane][k0 + kk];
        for (int c = 0; c < H; c++) {
            const float4* wr4 = (const float4*)(w2 + (size_t)c * FFD + k0);
            float p = 0.0f;
#pragma unroll
            for (int k4 = 0; k4 < 4; k4++) {
                float4 wq = wr4[k4];
                p += gv[4 * k4] * wq.x + gv[4 * k4 + 1] * wq.y +
                     gv[4 * k4 + 2] * wq.z + gv[4 * k4 + 3] * wq.w;
            }
            atomicAdd(&upd[lane][c], p);
        }
    }
    __syncthreads();

    // ---- phase 6: LN2 + write (wave 0) ----
    if (wv == 0) {
        float v[64];
        float s1 = 0.0f;
#pragma unroll
        for (int c = 0; c < 64; c++) { v[c] = z[lane][c] + upd[lane][c]; s1 += v[c]; }
        float mn = s1 * (1.0f / 64.0f);
        float s2 = 0.0f;
#pragma unroll
        for (int c = 0; c < 64; c++) { float d = v[c] - mn; s2 += d * d; }
        float rstd = 1.0f / sqrtf(s2 * (1.0f / 64.0f) + 1e-5f);
        int row = row0 + lane;
#pragma unroll
        for (int c = 0; c < 64; c++) {
            float res = (v[c] - mn) * rstd * g2[c] + b2n[c];
            if (!final_layer) {
                hbuf[(size_t)row * H + c] = res;
            } else {
                out[(size_t)row * H + c] = res;
                if (row % SEQ == SEQ - 1)
                    out[(size_t)NROW * H + (row / SEQ) * H + c] = res;
            }
        }
    }
}

extern "C" void kernel_launch(void* const* d_in, const int* in_sizes, int n_in,
                              void* d_out, int out_size, void* d_ws, size_t ws_size,
                              hipStream_t stream) {
    const float* x    = (const float*)d_in[0];
    const float* wih0 = (const float*)d_in[1];
    const float* whh0 = (const float*)d_in[2];
    const float* bih0 = (const float*)d_in[3];
    const float* bhh0 = (const float*)d_in[4];
    const float* wih1 = (const float*)d_in[5];
    const float* whh1 = (const float*)d_in[6];
    const float* bih1 = (const float*)d_in[7];
    const float* bhh1 = (const float*)d_in[8];
    const float* coeffs = (const float*)d_in[9];
    const float* ln1g = (const float*)d_in[10];
    const float* ln1b = (const float*)d_in[11];
    const float* w1   = (const float*)d_in[12];
    const float* b1   = (const float*)d_in[13];
    const float* w2   = (const float*)d_in[14];
    const float* b2   = (const float*)d_in[15];
    const float* ln2g = (const float*)d_in[16];
    const float* ln2b = (const float*)d_in[17];

    float* out = (float*)d_out;
    float* ws  = (float*)d_ws;
    float* xp0 = ws;                          // 16000*192 floats = 12.29 MB
    float* wtp = ws + (size_t)NROW * GDIM;    // 24576 floats
    float* hbuf = out;                        // reuse first 1,024,000 floats of d_out

    pack_wih0<<<(GDIM * DM + 255) / 256, 256, 0, stream>>>(wih0, wtp);
    xp0_gemm<<<NROW / 64, 192, 0, stream>>>(x, wtp, bih0, xp0);
    gru_fused<<<BSZ, 768, 0, stream>>>(xp0, whh0, bhh0, wih1, bih1, whh1, bhh1, hbuf);
    for (int l = 0; l < 2; l++) {
        sindy_layer_k<<<NROW / 64, 512, 0, stream>>>(
            hbuf, coeffs + (size_t)l * LIBN * H,
            ln1g + l * H, ln1b + l * H,
            w1 + (size_t)l * FFD * H, b1 + l * FFD,
            w2 + (size_t)l * H * FFD, b2 + l * H,
            ln2g + l * H, ln2b + l * H,
            out, l == 1);
    }
}

// Round 4
// 572.966 us; speedup vs baseline: 2.7986x; 1.7470x over previous
//
#include <hip/hip_runtime.h>
#include <hip/hip_bf16.h>
#include <math.h>

#define H 64
#define DM 128
#define GDIM 192      // 3*H
#define BSZ 32
#define SEQ 500
#define NROW (BSZ*SEQ)  // 16000
#define LIBN 2145
#define FFD 128
#define KPAD 2176     // 68*32 (theta K padded)
#define NKC 68        // K chunks of 32

typedef __attribute__((ext_vector_type(8))) short short8;   // bf16x8 MFMA operand
typedef __attribute__((ext_vector_type(4))) float f32x4;    // MFMA accumulator
typedef __attribute__((ext_vector_type(4))) unsigned u32x4;

__device__ __forceinline__ float sigf(float x) {
    return 1.0f / (1.0f + __expf(-x));
}
__device__ __forceinline__ float tanhfast(float x) {
    x = fminf(fmaxf(x, -15.0f), 15.0f);
    float t = __expf(-2.0f * x);
    return (1.0f - t) / (1.0f + t);
}
__device__ __forceinline__ short bf16r(float f) {   // fp32 -> bf16 rne
    unsigned u = __float_as_uint(f);
    unsigned r = (u + 0x7fffu + ((u >> 16) & 1u)) >> 16;
    return (short)r;
}

// ---------------- pack Wih0 (192,128) -> WTp[k4][g][e] for coalesced float4 loads ----
__global__ void pack_wih0(const float* __restrict__ w, float* __restrict__ wt) {
    int idx = blockIdx.x * 256 + threadIdx.x;
    if (idx >= GDIM * DM) return;
    int e  = idx & 3;
    int g  = (idx >> 2) % GDIM;
    int k4 = idx / (GDIM * 4);
    wt[idx] = w[g * DM + k4 * 4 + e];
}

// ---- prepack coef (2145x64, zero-pad to 2176) into bf16 B-fragment-linear order ----
// idx = ((kc*4 + nt)*64 + lane)*8 + j  ->  coef[k][c], k=kc*32+(lane>>4)*8+j, c=nt*16+(lane&15)
__global__ void pack_coef_frag(const float* __restrict__ coef, short* __restrict__ cp) {
    int idx = blockIdx.x * 256 + threadIdx.x;           // 68*4*64*8 = 139264
    int j = idx & 7, lane = (idx >> 3) & 63, nt = (idx >> 9) & 3, kc = idx >> 11;
    int k = kc * 32 + ((lane >> 4) << 3) + j;
    int c = nt * 16 + (lane & 15);
    float v = (k < LIBN) ? coef[(size_t)k * H + c] : 0.0f;
    cp[idx] = bf16r(v);
}
// ---- W1 (128,64): B = W1^T (K=64,N=128): idx=((kc*8+nt)*64+lane)*8+j -> W1[n][k] ----
__global__ void pack_w1_frag(const float* __restrict__ w1, short* __restrict__ wp) {
    int idx = blockIdx.x * 256 + threadIdx.x;           // 2*8*64*8 = 8192
    int j = idx & 7, lane = (idx >> 3) & 63, nt = (idx >> 9) & 7, kc = idx >> 12;
    int k = kc * 32 + ((lane >> 4) << 3) + j;
    int n = nt * 16 + (lane & 15);
    wp[idx] = bf16r(w1[(size_t)n * H + k]);
}
// ---- W2 (64,128): B = W2^T (K=128,N=64): idx=((kc*4+nt)*64+lane)*8+j -> W2[n][k] ----
__global__ void pack_w2_frag(const float* __restrict__ w2, short* __restrict__ wp) {
    int idx = blockIdx.x * 256 + threadIdx.x;           // 4*4*64*8 = 8192
    int j = idx & 7, lane = (idx >> 3) & 63, nt = (idx >> 9) & 3, kc = idx >> 11;
    int k = kc * 32 + ((lane >> 4) << 3) + j;
    int n = nt * 16 + (lane & 15);
    wp[idx] = bf16r(w2[(size_t)n * FFD + k]);
}

// ---------------- xp0 = x @ Wih0^T + bih0 : (16000,128)@(128,192) ------------------
__global__ __launch_bounds__(192, 2) void xp0_gemm(const float* __restrict__ x,
                                                   const float* __restrict__ wtp,
                                                   const float* __restrict__ bih0,
                                                   float* __restrict__ xp0) {
    __shared__ float xs[64][DM];
    int rb = blockIdx.x * 64;
    for (int idx = threadIdx.x; idx < 64 * 32; idx += 192) {
        int r = idx >> 5, k4 = idx & 31;
        ((f32x4*)xs[r])[k4] = ((const f32x4*)(x + (size_t)(rb + r) * DM))[k4];
    }
    __syncthreads();
    int g = threadIdx.x;
    float bias = bih0[g];
    float acc[64];
#pragma unroll
    for (int r = 0; r < 64; r++) acc[r] = bias;
    for (int k4 = 0; k4 < 32; k4++) {
        f32x4 w4 = ((const f32x4*)wtp)[k4 * GDIM + g];
#pragma unroll
        for (int r = 0; r < 64; r++) {
            f32x4 xv = ((f32x4*)xs[r])[k4];
            acc[r] += w4[0] * xv[0] + w4[1] * xv[1] + w4[2] * xv[2] + w4[3] * xv[3];
        }
    }
    for (int r = 0; r < 64; r++) xp0[(size_t)(rb + r) * GDIM + g] = acc[r];
}

// ---------------- fused 2-layer GRU scan (unchanged from R3) ------------------------
__global__ __launch_bounds__(768, 3) void gru_fused(const float* __restrict__ xp0,
                                                    const float* __restrict__ whh0,
                                                    const float* __restrict__ bhh0,
                                                    const float* __restrict__ wih1,
                                                    const float* __restrict__ bih1,
                                                    const float* __restrict__ whh1,
                                                    const float* __restrict__ bhh1,
                                                    float* __restrict__ hbuf) {
    int b = blockIdx.x;
    int tid = threadIdx.x;
    int wv = __builtin_amdgcn_readfirstlane(tid >> 6);
    int lane = tid & 63;
    int m = wv % 3;
    int q = wv / 3;
    int k0 = q * 16;

    __shared__ __align__(16) float h0s[H];
    __shared__ __align__(16) float h1s[H];
    __shared__ float part[3][4][GDIM];

    if (tid < H) { h0s[tid] = 0.0f; h1s[tid] = 0.0f; }

    const float* W = (m == 0) ? whh0 : (m == 1) ? wih1 : whh1;
    float wr[16], wz[16], wn[16];
#pragma unroll
    for (int k4 = 0; k4 < 4; k4++) {
        f32x4 a = ((const f32x4*)(W + (size_t)lane * H + k0))[k4];
        f32x4 c = ((const f32x4*)(W + (size_t)(H + lane) * H + k0))[k4];
        f32x4 d = ((const f32x4*)(W + (size_t)(2 * H + lane) * H + k0))[k4];
        wr[4*k4] = a[0]; wr[4*k4+1] = a[1]; wr[4*k4+2] = a[2]; wr[4*k4+3] = a[3];
        wz[4*k4] = c[0]; wz[4*k4+1] = c[1]; wz[4*k4+2] = c[2]; wz[4*k4+3] = c[3];
        wn[4*k4] = d[0]; wn[4*k4+1] = d[1]; wn[4*k4+2] = d[2]; wn[4*k4+3] = d[3];
    }

    float b0r = 0, b0z = 0, b0n = 0;
    float b1ir = 0, b1iz = 0, b1in = 0, b1hr = 0, b1hz = 0, b1hn = 0;
    float hreg0 = 0.0f, hreg1 = 0.0f;
    const float* xpb = xp0 + (size_t)b * SEQ * GDIM;
    float xr_c = 0, xz_c = 0, xn_c = 0, xr_n = 0, xz_n = 0, xn_n = 0;
    if (wv == 0) {
        b0r = bhh0[lane]; b0z = bhh0[H + lane]; b0n = bhh0[2 * H + lane];
        xr_c = xpb[lane]; xz_c = xpb[H + lane]; xn_c = xpb[2 * H + lane];
    } else if (wv == 2) {
        b1ir = bih1[lane]; b1iz = bih1[H + lane]; b1in = bih1[2 * H + lane];
        b1hr = bhh1[lane]; b1hz = bhh1[H + lane]; b1hn = bhh1[2 * H + lane];
    }
    __syncthreads();

    for (int s = 0; s <= SEQ; s++) {
        if (wv == 0 && s + 1 < SEQ) {
            const float* p = xpb + (size_t)(s + 1) * GDIM;
            xr_n = p[lane]; xz_n = p[H + lane]; xn_n = p[2 * H + lane];
        }
        const float* hv = (m == 2) ? h1s : h0s;
        float ar = 0, az = 0, an = 0;
#pragma unroll
        for (int t4 = 0; t4 < 4; t4++) {
            f32x4 h4 = ((const f32x4*)(hv + k0))[t4];
            ar += wr[4*t4] * h4[0] + wr[4*t4+1] * h4[1] + wr[4*t4+2] * h4[2] + wr[4*t4+3] * h4[3];
            az += wz[4*t4] * h4[0] + wz[4*t4+1] * h4[1] + wz[4*t4+2] * h4[2] + wz[4*t4+3] * h4[3];
            an += wn[4*t4] * h4[0] + wn[4*t4+1] * h4[1] + wn[4*t4+2] * h4[2] + wn[4*t4+3] * h4[3];
        }
        part[m][q][lane] = ar;
        part[m][q][H + lane] = az;
        part[m][q][2 * H + lane] = an;
        __syncthreads();

        if (wv == 0) {
            if (s < SEQ) {
                float gr = b0r, gz = b0z, gn = b0n;
#pragma unroll
                for (int qq = 0; qq < 4; qq++) {
                    gr += part[0][qq][lane];
                    gz += part[0][qq][H + lane];
                    gn += part[0][qq][2 * H + lane];
                }
                float rg = sigf(xr_c + gr);
                float zg = sigf(xz_c + gz);
                float ng = tanhfast(xn_c + rg * gn);
                hreg0 = (1.0f - zg) * ng + zg * hreg0;
                h0s[lane] = hreg0;
                xr_c = xr_n; xz_c = xz_n; xn_c = xn_n;
            }
        } else if (wv == 2) {
            if (s >= 1) {
                float xr1 = b1ir, xz1 = b1iz, xn1 = b1in;
                float gr1 = b1hr, gz1 = b1hz, gn1 = b1hn;
#pragma unroll
                for (int qq = 0; qq < 4; qq++) {
                    xr1 += part[1][qq][lane];
                    xz1 += part[1][qq][H + lane];
                    xn1 += part[1][qq][2 * H + lane];
                    gr1 += part[2][qq][lane];
                    gz1 += part[2][qq][H + lane];
                    gn1 += part[2][qq][2 * H + lane];
                }
                float rg = sigf(xr1 + gr1);
                float zg = sigf(xz1 + gz1);
                float ng = tanhfast(xn1 + rg * gn1);
                hreg1 = (1.0f - zg) * ng + zg * hreg1;
                h1s[lane] = hreg1;
                hbuf[((size_t)b * SEQ + (s - 1)) * H + lane] = hreg1;
            }
        }
        __syncthreads();
    }
}

// ---------------- MFMA SINDy layer: theta@coef + LN1 + FFN(gelu) + LN2 -------------
// 512 thr / 8 waves, 64 rows per block. 16x16x32 bf16 MFMA throughout.
// theta A-frags built in registers from LDS z-gathers (kmap: ze=[z,1,0] indices);
// coef/W1/W2 read as prepacked bf16 B-frags via coalesced global dwordx4.
__global__ __launch_bounds__(512) void sindy_mfma(float* __restrict__ hbuf,
                                                  const short* __restrict__ cpk,
                                                  const short* __restrict__ w1p,
                                                  const short* __restrict__ w2p,
                                                  const float* __restrict__ g1,
                                                  const float* __restrict__ b1n,
                                                  const float* __restrict__ bf1,
                                                  const float* __restrict__ bf2v,
                                                  const float* __restrict__ g2,
                                                  const float* __restrict__ b2n,
                                                  float* __restrict__ out,
                                                  int final_layer) {
    __shared__ float z[64 * 68];     // src rows (cols 64:=1.0, 65:=0.0), later LN1 out
    __shared__ float upd[64 * 68];   // theta@coef accumulator, later ff2 out
    __shared__ float ff[64 * 132];   // gelu(ff1)
    __shared__ unsigned kmap[KPAD];  // (a<<16|b) indices into ze
    __shared__ float bfs1[FFD], bfs2[H], g1s[H], b1s[H], g2s[H], b2s[H];

    int tid = threadIdx.x;
    int wv = __builtin_amdgcn_readfirstlane(tid >> 6);
    int lane = tid & 63;
    int row0 = blockIdx.x * 64;

    for (int idx = tid; idx < 64 * 16; idx += 512) {
        int r = idx >> 4, c4 = idx & 15;
        *(f32x4*)&z[r * 68 + c4 * 4] = *(const f32x4*)&hbuf[(size_t)(row0 + r) * H + c4 * 4];
    }
    for (int idx = tid; idx < 64 * 17; idx += 512)
        *(f32x4*)&upd[idx * 4] = (f32x4){0.f, 0.f, 0.f, 0.f};
    if (tid < 64) {
        z[tid * 68 + 64] = 1.0f; z[tid * 68 + 65] = 0.0f;
        z[tid * 68 + 66] = 0.0f; z[tid * 68 + 67] = 0.0f;
    }
    for (int k = tid; k < KPAD; k += 512) {
        unsigned a, b;
        if (k == 0) { a = 64; b = 64; }
        else if (k < 1 + H) { a = (unsigned)(k - 1); b = 64; }
        else if (k < LIBN) {
            int q = k - (1 + H);
            double s = sqrt(16641.0 - 8.0 * (double)q);     // exact at boundaries
            int i = (int)((129.0 - s) * 0.5);
            int base = 64 * i - (i * (i - 1)) / 2;
            a = (unsigned)i; b = (unsigned)(i + (q - base));
        } else { a = 65; b = 65; }
        kmap[k] = (a << 16) | b;
    }
    if (tid < FFD) bfs1[tid] = bf1[tid];
    if (tid < H) {
        bfs2[tid] = bf2v[tid];
        g1s[tid] = g1[tid]; b1s[tid] = b1n[tid];
        g2s[tid] = g2[tid]; b2s[tid] = b2n[tid];
    }
    __syncthreads();

    int kj0 = ((lane >> 4) << 3);           // 0,8,16,24 : lane's k-offset in frag
    int m0 = (wv & 3) * 16;                 // row tile
    int m = m0 + (lane & 15);               // A-operand row for this lane
    int rbase = m0 + ((lane >> 4) << 2);    // C/D row base for this lane
    int cb16 = lane & 15;                   // C/D col within tile
    const float* zrow = &z[m * 68];

    // ---- phase 1: upd = theta @ coef (k-split 2-way: p = wv>>2 takes kc%2==p) ----
    {
        int p = wv >> 2;
        f32x4 acc[4] = {{0,0,0,0},{0,0,0,0},{0,0,0,0},{0,0,0,0}};
        for (int kc = p; kc < NKC; kc += 2) {
            int kbase = kc * 32 + kj0;
            u32x4 km0 = *(const u32x4*)&kmap[kbase];
            u32x4 km1 = *(const u32x4*)&kmap[kbase + 4];
            short8 af;
            af[0] = bf16r(zrow[km0[0] >> 16] * zrow[km0[0] & 0xffff]);
            af[1] = bf16r(zrow[km0[1] >> 16] * zrow[km0[1] & 0xffff]);
            af[2] = bf16r(zrow[km0[2] >> 16] * zrow[km0[2] & 0xffff]);
            af[3] = bf16r(zrow[km0[3] >> 16] * zrow[km0[3] & 0xffff]);
            af[4] = bf16r(zrow[km1[0] >> 16] * zrow[km1[0] & 0xffff]);
            af[5] = bf16r(zrow[km1[1] >> 16] * zrow[km1[1] & 0xffff]);
            af[6] = bf16r(zrow[km1[2] >> 16] * zrow[km1[2] & 0xffff]);
            af[7] = bf16r(zrow[km1[3] >> 16] * zrow[km1[3] & 0xffff]);
            const short* cb = cpk + ((size_t)(kc * 4) * 64 + lane) * 8;
#pragma unroll
            for (int nt = 0; nt < 4; nt++) {
                short8 bf = *(const short8*)(cb + (size_t)nt * 512);
                acc[nt] = __builtin_amdgcn_mfma_f32_16x16x32_bf16(af, bf, acc[nt], 0, 0, 0);
            }
        }
#pragma unroll
        for (int nt = 0; nt < 4; nt++)
#pragma unroll
            for (int r = 0; r < 4; r++)
                atomicAdd(&upd[(rbase + r) * 68 + nt * 16 + cb16], acc[nt][r]);
    }
    __syncthreads();

    // ---- phase 2: LN1 (wave 0; lane = row) -> z ----
    if (wv == 0) {
        float v[64];
        float s1 = 0.0f;
#pragma unroll
        for (int c = 0; c < 64; c++) { v[c] = z[lane * 68 + c] + upd[lane * 68 + c]; s1 += v[c]; }
        float mn = s1 * (1.0f / 64.0f);
        float s2 = 0.0f;
#pragma unroll
        for (int c = 0; c < 64; c++) { float d = v[c] - mn; s2 += d * d; }
        float rstd = 1.0f / sqrtf(s2 * (1.0f / 64.0f) + 1e-5f);
#pragma unroll
        for (int c = 0; c < 64; c++)
            z[lane * 68 + c] = (v[c] - mn) * rstd * g1s[c] + b1s[c];
    }
    __syncthreads();

    // ---- phase 3: ff = gelu(LN1 @ W1^T + b1) : C 64x128, waves own 4 n-tiles ----
    {
        int nq = wv >> 2;
        f32x4 acc[4] = {{0,0,0,0},{0,0,0,0},{0,0,0,0},{0,0,0,0}};
#pragma unroll
        for (int kc = 0; kc < 2; kc++) {
            f32x4 za = *(const f32x4*)&z[m * 68 + kc * 32 + kj0];
            f32x4 zb = *(const f32x4*)&z[m * 68 + kc * 32 + kj0 + 4];
            short8 af;
            af[0] = bf16r(za[0]); af[1] = bf16r(za[1]); af[2] = bf16r(za[2]); af[3] = bf16r(za[3]);
            af[4] = bf16r(zb[0]); af[5] = bf16r(zb[1]); af[6] = bf16r(zb[2]); af[7] = bf16r(zb[3]);
#pragma unroll
            for (int t = 0; t < 4; t++) {
                int nt = nq * 4 + t;
                short8 bf = *(const short8*)(w1p + ((size_t)(kc * 8 + nt) * 64 + lane) * 8);
                acc[t] = __builtin_amdgcn_mfma_f32_16x16x32_bf16(af, bf, acc[t], 0, 0, 0);
            }
        }
#pragma unroll
        for (int t = 0; t < 4; t++) {
            int col = (nq * 4 + t) * 16 + cb16;
#pragma unroll
            for (int r = 0; r < 4; r++) {
                float v = acc[t][r] + bfs1[col];
                ff[(rbase + r) * 132 + col] = 0.5f * v * (1.0f + erff(v * 0.70710678118654752f));
            }
        }
    }
    __syncthreads();

    // ---- phase 5: upd = ff @ W2^T + b2 : C 64x64, waves own 2 n-tiles ----
    {
        int nh = wv >> 2;
        f32x4 acc[2] = {{0,0,0,0},{0,0,0,0}};
        const float* frow = &ff[m * 132];
#pragma unroll
        for (int kc = 0; kc < 4; kc++) {
            f32x4 fa = *(const f32x4*)&frow[kc * 32 + kj0];
            f32x4 fb = *(const f32x4*)&frow[kc * 32 + kj0 + 4];
            short8 af;
            af[0] = bf16r(fa[0]); af[1] = bf16r(fa[1]); af[2] = bf16r(fa[2]); af[3] = bf16r(fa[3]);
            af[4] = bf16r(fb[0]); af[5] = bf16r(fb[1]); af[6] = bf16r(fb[2]); af[7] = bf16r(fb[3]);
#pragma unroll
            for (int t = 0; t < 2; t++) {
                int nt = nh * 2 + t;
                short8 bf = *(const short8*)(w2p + ((size_t)(kc * 4 + nt) * 64 + lane) * 8);
                acc[t] = __builtin_amdgcn_mfma_f32_16x16x32_bf16(af, bf, acc[t], 0, 0, 0);
            }
        }
#pragma unroll
        for (int t = 0; t < 2; t++) {
            int col = (nh * 2 + t) * 16 + cb16;
#pragma unroll
            for (int r = 0; r < 4; r++)
                upd[(rbase + r) * 68 + col] = acc[t][r] + bfs2[col];
        }
    }
    __syncthreads();

    // ---- phase 6: LN2 + write (wave 0) ----
    if (wv == 0) {
        float v[64];
        float s1 = 0.0f;
#pragma unroll
        for (int c = 0; c < 64; c++) { v[c] = z[lane * 68 + c] + upd[lane * 68 + c]; s1 += v[c]; }
        float mn = s1 * (1.0f / 64.0f);
        float s2 = 0.0f;
#pragma unroll
        for (int c = 0; c < 64; c++) { float d = v[c] - mn; s2 += d * d; }
        float rstd = 1.0f / sqrtf(s2 * (1.0f / 64.0f) + 1e-5f);
        int row = row0 + lane;
#pragma unroll
        for (int c = 0; c < 64; c++) {
            float res = (v[c] - mn) * rstd * g2s[c] + b2s[c];
            if (!final_layer) {
                hbuf[(size_t)row * H + c] = res;
            } else {
                out[(size_t)row * H + c] = res;
                if (row % SEQ == SEQ - 1)
                    out[(size_t)NROW * H + (row / SEQ) * H + c] = res;
            }
        }
    }
}

extern "C" void kernel_launch(void* const* d_in, const int* in_sizes, int n_in,
                              void* d_out, int out_size, void* d_ws, size_t ws_size,
                              hipStream_t stream) {
    const float* x    = (const float*)d_in[0];
    const float* wih0 = (const float*)d_in[1];
    const float* whh0 = (const float*)d_in[2];
    const float* bih0 = (const float*)d_in[3];
    const float* bhh0 = (const float*)d_in[4];
    const float* wih1 = (const float*)d_in[5];
    const float* whh1 = (const float*)d_in[6];
    const float* bih1 = (const float*)d_in[7];
    const float* bhh1 = (const float*)d_in[8];
    const float* coeffs = (const float*)d_in[9];
    const float* ln1g = (const float*)d_in[10];
    const float* ln1b = (const float*)d_in[11];
    const float* w1   = (const float*)d_in[12];
    const float* b1   = (const float*)d_in[13];
    const float* w2   = (const float*)d_in[14];
    const float* b2   = (const float*)d_in[15];
    const float* ln2g = (const float*)d_in[16];
    const float* ln2b = (const float*)d_in[17];

    float* out = (float*)d_out;
    float* ws  = (float*)d_ws;
    float* xp0 = ws;                               // 16000*192 = 3,072,000 floats
    float* wtp = ws + (size_t)NROW * GDIM;         // 24,576 floats
    short* bfa = (short*)(wtp + GDIM * DM);        // bf16 fragment area
    short* cpk[2] = { bfa, bfa + 139264 };
    short* w1pk[2] = { bfa + 2 * 139264, bfa + 2 * 139264 + 8192 };
    short* w2pk[2] = { bfa + 2 * 139264 + 2 * 8192, bfa + 2 * 139264 + 3 * 8192 };
    float* hbuf = out;                             // reuse first 1,024,000 floats of d_out

    pack_wih0<<<(GDIM * DM + 255) / 256, 256, 0, stream>>>(wih0, wtp);
    for (int l = 0; l < 2; l++) {
        pack_coef_frag<<<139264 / 256, 256, 0, stream>>>(coeffs + (size_t)l * LIBN * H, cpk[l]);
        pack_w1_frag<<<8192 / 256, 256, 0, stream>>>(w1 + (size_t)l * FFD * H, w1pk[l]);
        pack_w2_frag<<<8192 / 256, 256, 0, stream>>>(w2 + (size_t)l * H * FFD, w2pk[l]);
    }
    xp0_gemm<<<NROW / 64, 192, 0, stream>>>(x, wtp, bih0, xp0);
    gru_fused<<<BSZ, 768, 0, stream>>>(xp0, whh0, bhh0, wih1, bih1, whh1, bhh1, hbuf);
    for (int l = 0; l < 2; l++) {
        sindy_mfma<<<NROW / 64, 512, 0, stream>>>(
            hbuf, cpk[l], w1pk[l], w2pk[l],
            ln1g + l * H, ln1b + l * H, b1 + l * FFD,
            b2 + l * H, ln2g + l * H, ln2b + l * H,
            out, l == 1);
    }
}